// Round 1
// baseline (716.850 us; speedup 1.0000x reference)
//
#include <hip/hip_runtime.h>
#include <hip/hip_bf16.h>
#include <cstdint>
#include <cstddef>

// ---------------------------------------------------------------------------
// GCN link predictor: h1 = relu(Â(xW1)+b1); h2 = Â(h1W2)+b2; out = rowdot(h2[i],h2[j])
// Â built as CSR-by-destination each call (histogram -> scan -> fill).
// All math f32 (threshold 2.7e-2 abs @ |out|~468 is too tight for bf16 MFMA).
// ---------------------------------------------------------------------------

// ---------------- degree histogram ----------------
__global__ void k_hist(const int* __restrict__ col, int* __restrict__ cnt, int E) {
    int e = blockIdx.x * blockDim.x + threadIdx.x;
    if (e < E) atomicAdd(&cnt[col[e]], 1);
}

__global__ void k_dinv(const int* __restrict__ cnt, float* __restrict__ dinv, int n) {
    int v = blockIdx.x * blockDim.x + threadIdx.x;
    if (v < n) dinv[v] = rsqrtf((float)(cnt[v] + 1));  // +1 self loop
}

// ---------------- exclusive scan over cnt -> rowptr ----------------
__global__ void k_scan1(const int* __restrict__ cnt, int* __restrict__ incl,
                        int* __restrict__ bsum, int n) {
    __shared__ int s[1024];
    int tid = threadIdx.x;
    int g = blockIdx.x * 1024 + tid;
    s[tid] = (g < n) ? cnt[g] : 0;
    __syncthreads();
    for (int off = 1; off < 1024; off <<= 1) {
        int add = (tid >= off) ? s[tid - off] : 0;
        __syncthreads();
        s[tid] += add;
        __syncthreads();
    }
    if (g < n) incl[g] = s[tid];
    if (tid == 1023) bsum[blockIdx.x] = s[1023];
}

__global__ void k_scan2(int* bsum, int nb) {
    if (threadIdx.x == 0 && blockIdx.x == 0) {
        int run = 0;
        for (int b = 0; b < nb; ++b) { int t = bsum[b]; bsum[b] = run; run += t; }
    }
}

__global__ void k_scan3(const int* __restrict__ incl, const int* __restrict__ bsum,
                        const int* __restrict__ cnt, int* __restrict__ rowptr,
                        int n, int E) {
    int v = blockIdx.x * blockDim.x + threadIdx.x;
    if (v < n) rowptr[v] = incl[v] + bsum[v >> 10] - cnt[v];
    if (v == 0) rowptr[n] = E;
}

// ---------------- CSR fill (order within segment arbitrary; f32 sum order diff ok)
__global__ void k_fill(const int* __restrict__ row, const int* __restrict__ col,
                       const int* __restrict__ rowptr, int* __restrict__ fill,
                       int* __restrict__ csr, int E) {
    int e = blockIdx.x * blockDim.x + threadIdx.x;
    if (e < E) {
        int c = col[e];
        int p = rowptr[c] + atomicAdd(&fill[c], 1);
        csr[p] = row[e];
    }
}

// ---------------- f32 SGEMM, C[M,BN] = A[M,K] @ B[K,BN], N == BN ----------------
template<int BM, int BN, int BK, int NTHR>
__launch_bounds__(NTHR)
__global__ void sgemm_kernel(const float* __restrict__ A, const float* __restrict__ B,
                             float* __restrict__ C, int M, int K) {
    constexpr int TM = 8, TN = 8;
    constexpr int NX = BN / TN;           // threads along N
    constexpr int NY = BM / TM;           // threads along M
    static_assert(NX * NY == NTHR, "thread count mismatch");
    __shared__ float As[BK][BM];          // transposed A tile
    __shared__ float Bs[BK][BN];

    const int tid = threadIdx.x;
    const int tx = tid % NX;
    const int ty = tid / NX;
    const int m0 = blockIdx.x * BM;

    float acc[TM][TN] = {};

    constexpr int A_LOADS = BM * BK / (4 * NTHR);
    constexpr int B_LOADS = BK * BN / (4 * NTHR);

    for (int k0 = 0; k0 < K; k0 += BK) {
        __syncthreads();
        #pragma unroll
        for (int i = 0; i < A_LOADS; ++i) {
            int slot = tid + i * NTHR;            // float4 slots
            int row = slot / (BK / 4);
            int kq  = slot % (BK / 4);
            float4 v = make_float4(0.f, 0.f, 0.f, 0.f);
            int gr = m0 + row;
            if (gr < M) v = *(const float4*)(A + (size_t)gr * K + k0 + kq * 4);
            As[kq * 4 + 0][row] = v.x;
            As[kq * 4 + 1][row] = v.y;
            As[kq * 4 + 2][row] = v.z;
            As[kq * 4 + 3][row] = v.w;
        }
        #pragma unroll
        for (int i = 0; i < B_LOADS; ++i) {
            int slot = tid + i * NTHR;
            int row = slot / (BN / 4);
            int cq  = slot % (BN / 4);
            *(float4*)&Bs[row][cq * 4] = *(const float4*)(B + (size_t)(k0 + row) * BN + cq * 4);
        }
        __syncthreads();
        for (int k = 0; k < BK; ++k) {
            float a[TM], b[TN];
            // split micro-tile halves: 2-way-bank-aliased b128 reads (free)
            *(float4*)&a[0] = *(const float4*)&As[k][ty * 4];
            *(float4*)&a[4] = *(const float4*)&As[k][BM / 2 + ty * 4];
            *(float4*)&b[0] = *(const float4*)&Bs[k][tx * 4];
            *(float4*)&b[4] = *(const float4*)&Bs[k][BN / 2 + tx * 4];
            #pragma unroll
            for (int i = 0; i < TM; ++i)
                #pragma unroll
                for (int j = 0; j < TN; ++j)
                    acc[i][j] += a[i] * b[j];
        }
    }

    #pragma unroll
    for (int ih = 0; ih < 2; ++ih) {
        #pragma unroll
        for (int i = 0; i < 4; ++i) {
            int r = m0 + ih * (BM / 2) + ty * 4 + i;
            if (r < M) {
                float* cp = C + (size_t)r * BN;
                *(float4*)(cp + tx * 4) =
                    make_float4(acc[ih * 4 + i][0], acc[ih * 4 + i][1],
                                acc[ih * 4 + i][2], acc[ih * 4 + i][3]);
                *(float4*)(cp + BN / 2 + tx * 4) =
                    make_float4(acc[ih * 4 + i][4], acc[ih * 4 + i][5],
                                acc[ih * 4 + i][6], acc[ih * 4 + i][7]);
            }
        }
    }
}

// ---------------- pull-SpMM: out[v] = dinv[v]*(sum_e h[src]*dinv[src] + h[v]*dinv[v]) + b
template<int F, bool RELU>
__launch_bounds__(256)
__global__ void k_spmm(const float* __restrict__ h, const int* __restrict__ rowptr,
                       const int* __restrict__ csr, const float* __restrict__ dinv,
                       const float* __restrict__ bias, float* __restrict__ out, int n) {
    int wid  = (blockIdx.x * 256 + threadIdx.x) >> 6;   // wave id = node id
    int lane = threadIdx.x & 63;
    if (wid >= n) return;
    const int v = wid;
    const int beg = rowptr[v], end = rowptr[v + 1];
    float acc0 = 0.f, acc1 = 0.f;

    for (int base = beg; base < end; base += 64) {
        int e = base + lane;
        int sv = 0; float wv = 0.f;
        if (e < end) { sv = csr[e]; wv = dinv[sv]; }
        int m = min(64, end - base);
        for (int j = 0; j < m; ++j) {
            int s   = __shfl(sv, j, 64);
            float w = __shfl(wv, j, 64);
            if (F == 128) {
                float2 hv = *(const float2*)(h + (size_t)s * F + lane * 2);
                acc0 += hv.x * w;
                acc1 += hv.y * w;
            } else {
                acc0 += h[(size_t)s * F + lane] * w;
            }
        }
    }

    const float ws = dinv[v];
    if (F == 128) {
        float2 hv = *(const float2*)(h + (size_t)v * F + lane * 2);
        float r0 = (acc0 + hv.x * ws) * ws + bias[lane * 2];
        float r1 = (acc1 + hv.y * ws) * ws + bias[lane * 2 + 1];
        if (RELU) { r0 = fmaxf(r0, 0.f); r1 = fmaxf(r1, 0.f); }
        *(float2*)(out + (size_t)v * F + lane * 2) = make_float2(r0, r1);
    } else {
        float hv = h[(size_t)v * F + lane];
        float r0 = (acc0 + hv * ws) * ws + bias[lane];
        if (RELU) r0 = fmaxf(r0, 0.f);
        out[(size_t)v * F + lane] = r0;
    }
}

// ---------------- edge dot: out[e] = <h2[a], h2[b]> over 64 dims ----------------
__launch_bounds__(256)
__global__ void k_dot(const float* __restrict__ h2, const int* __restrict__ pos,
                      const int* __restrict__ neg, float* __restrict__ out,
                      int ep, int ne2) {
    int wid  = (blockIdx.x * 256 + threadIdx.x) >> 6;   // wave id = output edge
    int lane = threadIdx.x & 63;
    if (wid >= ne2) return;
    const int* p = (wid < ep) ? pos : neg;
    int e = (wid < ep) ? wid : wid - ep;
    int a = p[e];        // te[0] = source
    int b = p[ep + e];   // te[1] = target
    float val = h2[(size_t)a * 64 + lane] * h2[(size_t)b * 64 + lane];
    #pragma unroll
    for (int off = 32; off; off >>= 1) val += __shfl_down(val, off, 64);
    if (lane == 0) out[wid] = val;
}

// ---------------------------------------------------------------------------
extern "C" void kernel_launch(void* const* d_in, const int* in_sizes, int n_in,
                              void* d_out, int out_size, void* d_ws, size_t ws_size,
                              hipStream_t stream) {
    const float* x  = (const float*)d_in[0];
    const int*   ei = (const int*)d_in[1];
    const int*   pe = (const int*)d_in[2];
    const int*   ng = (const int*)d_in[3];
    const float* W1 = (const float*)d_in[4];
    const float* b1 = (const float*)d_in[5];
    const float* W2 = (const float*)d_in[6];
    const float* b2 = (const float*)d_in[7];
    float* out = (float*)d_out;

    const int F_IN = 256, H1 = 128, H2 = 64;
    const int n  = in_sizes[0] / F_IN;     // 100000
    const int E  = in_sizes[1] / 2;        // 1600000
    const int EP = in_sizes[2] / 2;        // 100000

    const int* row = ei;
    const int* col = ei + E;

    // ---- workspace layout (256B aligned) ----
    uint8_t* w = (uint8_t*)d_ws;
    auto alloc = [&](size_t bytes) {
        uint8_t* p = w;
        w += (bytes + 255) & ~(size_t)255;
        return p;
    };
    int*   cnt    = (int*)alloc((size_t)n * 4);
    int*   fill   = (int*)alloc((size_t)n * 4);
    float* dinv   = (float*)alloc((size_t)n * 4);
    int*   rowptr = (int*)alloc((size_t)(n + 1) * 4);
    int*   incl   = (int*)alloc((size_t)n * 4);
    int*   bsum   = (int*)alloc(512);
    int*   csr    = (int*)alloc((size_t)E * 4);
    float* bufA   = (float*)alloc((size_t)n * 128 * 4);   // h, then {t2, h2}
    float* bufB   = (float*)alloc((size_t)n * 128 * 4);   // h1
    float* h  = bufA;
    float* h1 = bufB;
    float* t2 = bufA;                      // reuse: h dead after spmm1
    float* h2 = bufA + (size_t)n * 64;     // disjoint from t2

    // ---- zero counters (ws is poisoned 0xAA every call) ----
    hipMemsetAsync(cnt,  0, (size_t)n * 4, stream);
    hipMemsetAsync(fill, 0, (size_t)n * 4, stream);

    const int TPB = 256;
    int ebl = (E + TPB - 1) / TPB;
    int nbl = (n + TPB - 1) / TPB;
    int nscan = (n + 1023) / 1024;

    k_hist<<<ebl, TPB, 0, stream>>>(col, cnt, E);
    k_dinv<<<nbl, TPB, 0, stream>>>(cnt, dinv, n);
    k_scan1<<<nscan, 1024, 0, stream>>>(cnt, incl, bsum, n);
    k_scan2<<<1, 64, 0, stream>>>(bsum, nscan);
    k_scan3<<<nbl, TPB, 0, stream>>>(incl, bsum, cnt, rowptr, n, E);
    k_fill<<<ebl, TPB, 0, stream>>>(row, col, rowptr, fill, csr, E);

    // layer 1: h = x @ W1 ; h1 = relu(Â h + b1)
    sgemm_kernel<128, 128, 32, 256><<<(n + 127) / 128, 256, 0, stream>>>(x, W1, h, n, F_IN);
    k_spmm<128, true><<<(n + 3) / 4, 256, 0, stream>>>(h, rowptr, csr, dinv, b1, h1, n);

    // layer 2: t2 = h1 @ W2 ; h2 = Â t2 + b2
    sgemm_kernel<128, 64, 32, 128><<<(n + 127) / 128, 128, 0, stream>>>(h1, W2, t2, n, H1);
    k_spmm<64, false><<<(n + 3) / 4, 256, 0, stream>>>(t2, rowptr, csr, dinv, b2, h2, n);

    // link prediction dots
    int ne2 = 2 * EP;
    k_dot<<<(ne2 + 3) / 4, 256, 0, stream>>>(h2, pe, ng, out, EP, ne2);
}

// Round 4
// 632.554 us; speedup vs baseline: 1.1333x; 1.1333x over previous
//
#include <hip/hip_runtime.h>
#include <hip/hip_bf16.h>
#include <cstdint>
#include <cstddef>

// ---------------------------------------------------------------------------
// GCN link predictor: h1 = relu(Â(xW1)+b1); h2 = Â(h1W2)+b2; out = rowdot(h2[i],h2[j])
// Â built as CSR-by-destination each call (histogram -> scan -> fill).
// dinv[src] folded into GEMM epilogue: h' = (x@W)*dinv[row]; aggregation = pure sum.
// SpMM: full-wave broadcast gather (round-1-proven structure), 8-deep unroll for MLP.
// ---------------------------------------------------------------------------

// ---------------- degree histogram ----------------
__global__ void k_hist(const int* __restrict__ col, int* __restrict__ cnt, int E) {
    int e = blockIdx.x * blockDim.x + threadIdx.x;
    if (e < E) atomicAdd(&cnt[col[e]], 1);
}

__global__ void k_dinv(const int* __restrict__ cnt, float* __restrict__ dinv, int n) {
    int v = blockIdx.x * blockDim.x + threadIdx.x;
    if (v < n) dinv[v] = rsqrtf((float)(cnt[v] + 1));  // +1 self loop
}

// ---------------- exclusive scan over cnt -> rowptr ----------------
__global__ void k_scan1(const int* __restrict__ cnt, int* __restrict__ incl,
                        int* __restrict__ bsum, int n) {
    __shared__ int s[1024];
    int tid = threadIdx.x;
    int g = blockIdx.x * 1024 + tid;
    s[tid] = (g < n) ? cnt[g] : 0;
    __syncthreads();
    for (int off = 1; off < 1024; off <<= 1) {
        int add = (tid >= off) ? s[tid - off] : 0;
        __syncthreads();
        s[tid] += add;
        __syncthreads();
    }
    if (g < n) incl[g] = s[tid];
    if (tid == 1023) bsum[blockIdx.x] = s[1023];
}

// parallel block-sum scan (nb <= 128)
__global__ void k_scan2(int* bsum, int nb) {
    __shared__ int s[128];
    int t = threadIdx.x;
    int v = (t < nb) ? bsum[t] : 0;
    s[t] = v;
    __syncthreads();
    for (int off = 1; off < 128; off <<= 1) {
        int add = (t >= off) ? s[t - off] : 0;
        __syncthreads();
        s[t] += add;
        __syncthreads();
    }
    if (t < nb) bsum[t] = s[t] - v;   // exclusive
}

__global__ void k_scan3(const int* __restrict__ incl, const int* __restrict__ bsum,
                        const int* __restrict__ cnt, int* __restrict__ rowptr,
                        int n, int E) {
    int v = blockIdx.x * blockDim.x + threadIdx.x;
    if (v < n) rowptr[v] = incl[v] + bsum[v >> 10] - cnt[v];
    if (v == 0) rowptr[n] = E;
}

// ---------------- CSR fill: reuse cnt as a countdown cursor ----------------
__global__ void k_fill(const int* __restrict__ row, const int* __restrict__ col,
                       const int* __restrict__ rowptr, int* __restrict__ cnt,
                       int* __restrict__ csr, int E) {
    int e = blockIdx.x * blockDim.x + threadIdx.x;
    if (e < E) {
        int c = col[e];
        int old = atomicSub(&cnt[c], 1);      // old in [1..deg], unique slot
        csr[rowptr[c] + old - 1] = row[e];
    }
}

// ---------------- f32 SGEMM, C[M,BN] = (A[M,K] @ B[K,BN]) * rscale[row] ----------------
template<int BM, int BN, int BK, int NTHR>
__launch_bounds__(NTHR)
__global__ void sgemm_kernel(const float* __restrict__ A, const float* __restrict__ B,
                             float* __restrict__ C, const float* __restrict__ rscale,
                             int M, int K) {
    constexpr int TM = 8, TN = 8;
    constexpr int NX = BN / TN;           // threads along N
    constexpr int NY = BM / TM;           // threads along M
    static_assert(NX * NY == NTHR, "thread count mismatch");
    __shared__ float As[BK][BM];          // transposed A tile
    __shared__ float Bs[BK][BN];

    const int tid = threadIdx.x;
    const int tx = tid % NX;
    const int ty = tid / NX;
    const int m0 = blockIdx.x * BM;

    float acc[TM][TN] = {};

    constexpr int A_LOADS = BM * BK / (4 * NTHR);
    constexpr int B_LOADS = BK * BN / (4 * NTHR);

    for (int k0 = 0; k0 < K; k0 += BK) {
        __syncthreads();
        #pragma unroll
        for (int i = 0; i < A_LOADS; ++i) {
            int slot = tid + i * NTHR;            // float4 slots
            int row = slot / (BK / 4);
            int kq  = slot % (BK / 4);
            float4 v = make_float4(0.f, 0.f, 0.f, 0.f);
            int gr = m0 + row;
            if (gr < M) v = *(const float4*)(A + (size_t)gr * K + k0 + kq * 4);
            As[kq * 4 + 0][row] = v.x;
            As[kq * 4 + 1][row] = v.y;
            As[kq * 4 + 2][row] = v.z;
            As[kq * 4 + 3][row] = v.w;
        }
        #pragma unroll
        for (int i = 0; i < B_LOADS; ++i) {
            int slot = tid + i * NTHR;
            int row = slot / (BN / 4);
            int cq  = slot % (BN / 4);
            *(float4*)&Bs[row][cq * 4] = *(const float4*)(B + (size_t)(k0 + row) * BN + cq * 4);
        }
        __syncthreads();
        for (int k = 0; k < BK; ++k) {
            float a[TM], b[TN];
            *(float4*)&a[0] = *(const float4*)&As[k][ty * 4];
            *(float4*)&a[4] = *(const float4*)&As[k][BM / 2 + ty * 4];
            *(float4*)&b[0] = *(const float4*)&Bs[k][tx * 4];
            *(float4*)&b[4] = *(const float4*)&Bs[k][BN / 2 + tx * 4];
            #pragma unroll
            for (int i = 0; i < TM; ++i)
                #pragma unroll
                for (int j = 0; j < TN; ++j)
                    acc[i][j] += a[i] * b[j];
        }
    }

    #pragma unroll
    for (int ih = 0; ih < 2; ++ih) {
        #pragma unroll
        for (int i = 0; i < 4; ++i) {
            int r = m0 + ih * (BM / 2) + ty * 4 + i;
            if (r < M) {
                float sc = rscale[r];
                float* cp = C + (size_t)r * BN;
                *(float4*)(cp + tx * 4) =
                    make_float4(acc[ih * 4 + i][0] * sc, acc[ih * 4 + i][1] * sc,
                                acc[ih * 4 + i][2] * sc, acc[ih * 4 + i][3] * sc);
                *(float4*)(cp + BN / 2 + tx * 4) =
                    make_float4(acc[ih * 4 + i][4] * sc, acc[ih * 4 + i][5] * sc,
                                acc[ih * 4 + i][6] * sc, acc[ih * 4 + i][7] * sc);
            }
        }
    }
}

// ---------------- pull-SpMM on prescaled hp: out[v] = dinv[v]*(sum_e hp[src] + hp[v]) + b
// Full-wave broadcast (round-1 structure): lane owns feature chunk, edges broadcast
// via shfl; 8-deep manual unroll = 8 independent gathers in flight. No divergence.
template<int F, bool RELU>
__launch_bounds__(256)
__global__ void k_spmm(const float* __restrict__ hp, const int* __restrict__ rowptr,
                       const int* __restrict__ csr, const float* __restrict__ dinv,
                       const float* __restrict__ bias, float* __restrict__ out, int n) {
    const int wid  = (blockIdx.x * 256 + threadIdx.x) >> 6;   // wave id = node id
    const int lane = threadIdx.x & 63;
    if (wid >= n) return;
    const int v = wid;
    const int beg = rowptr[v], end = rowptr[v + 1];

    float acc0 = 0.f, acc1 = 0.f;   // F=128: features {2*lane, 2*lane+1}; F=64: {lane}

    for (int base = beg; base < end; base += 64) {
        const int e  = base + lane;
        const int sv = (e < end) ? csr[e] : 0;
        const int m  = min(64, end - base);
        int j = 0;
        for (; j + 8 <= m; j += 8) {        // 8 independent gathers in flight
            int s0 = __shfl(sv, j + 0, 64), s1 = __shfl(sv, j + 1, 64);
            int s2 = __shfl(sv, j + 2, 64), s3 = __shfl(sv, j + 3, 64);
            int s4 = __shfl(sv, j + 4, 64), s5 = __shfl(sv, j + 5, 64);
            int s6 = __shfl(sv, j + 6, 64), s7 = __shfl(sv, j + 7, 64);
            if (F == 128) {
                float2 a0 = *(const float2*)(hp + (size_t)s0 * F + lane * 2);
                float2 a1 = *(const float2*)(hp + (size_t)s1 * F + lane * 2);
                float2 a2 = *(const float2*)(hp + (size_t)s2 * F + lane * 2);
                float2 a3 = *(const float2*)(hp + (size_t)s3 * F + lane * 2);
                float2 a4 = *(const float2*)(hp + (size_t)s4 * F + lane * 2);
                float2 a5 = *(const float2*)(hp + (size_t)s5 * F + lane * 2);
                float2 a6 = *(const float2*)(hp + (size_t)s6 * F + lane * 2);
                float2 a7 = *(const float2*)(hp + (size_t)s7 * F + lane * 2);
                acc0 += ((a0.x + a1.x) + (a2.x + a3.x)) + ((a4.x + a5.x) + (a6.x + a7.x));
                acc1 += ((a0.y + a1.y) + (a2.y + a3.y)) + ((a4.y + a5.y) + (a6.y + a7.y));
            } else {
                float a0 = hp[(size_t)s0 * F + lane], a1 = hp[(size_t)s1 * F + lane];
                float a2 = hp[(size_t)s2 * F + lane], a3 = hp[(size_t)s3 * F + lane];
                float a4 = hp[(size_t)s4 * F + lane], a5 = hp[(size_t)s5 * F + lane];
                float a6 = hp[(size_t)s6 * F + lane], a7 = hp[(size_t)s7 * F + lane];
                acc0 += ((a0 + a1) + (a2 + a3)) + ((a4 + a5) + (a6 + a7));
            }
        }
        for (; j < m; ++j) {
            int s = __shfl(sv, j, 64);
            if (F == 128) {
                float2 a = *(const float2*)(hp + (size_t)s * F + lane * 2);
                acc0 += a.x; acc1 += a.y;
            } else {
                acc0 += hp[(size_t)s * F + lane];
            }
        }
    }

    const float d = dinv[v];
    if (F == 128) {
        float2 self = *(const float2*)(hp + (size_t)v * F + lane * 2);
        float r0 = (acc0 + self.x) * d + bias[lane * 2];
        float r1 = (acc1 + self.y) * d + bias[lane * 2 + 1];
        if (RELU) { r0 = fmaxf(r0, 0.f); r1 = fmaxf(r1, 0.f); }
        *(float2*)(out + (size_t)v * F + lane * 2) = make_float2(r0, r1);
    } else {
        float self = hp[(size_t)v * F + lane];
        float r = (acc0 + self) * d + bias[lane];
        if (RELU) r = fmaxf(r, 0.f);
        out[(size_t)v * F + lane] = r;
    }
}

// ---------------- edge dot: 16 lanes per edge, float4 loads ----------------
__launch_bounds__(256)
__global__ void k_dot(const float* __restrict__ h2, const int* __restrict__ pos,
                      const int* __restrict__ neg, float* __restrict__ out,
                      int ep, int ne2) {
    int gid = (blockIdx.x * 256 + threadIdx.x) >> 4;   // 16-lane group = one edge
    int l = threadIdx.x & 15;
    if (gid >= ne2) return;
    const int* p = (gid < ep) ? pos : neg;
    int e = (gid < ep) ? gid : gid - ep;
    int a = p[e];        // te[0] = source
    int b = p[ep + e];   // te[1] = target
    float4 va = *(const float4*)(h2 + (size_t)a * 64 + l * 4);
    float4 vb = *(const float4*)(h2 + (size_t)b * 64 + l * 4);
    float s = va.x * vb.x + va.y * vb.y + va.z * vb.z + va.w * vb.w;
    s += __shfl_xor(s, 8, 64);
    s += __shfl_xor(s, 4, 64);
    s += __shfl_xor(s, 2, 64);
    s += __shfl_xor(s, 1, 64);
    if (l == 0) out[gid] = s;
}

// ---------------------------------------------------------------------------
extern "C" void kernel_launch(void* const* d_in, const int* in_sizes, int n_in,
                              void* d_out, int out_size, void* d_ws, size_t ws_size,
                              hipStream_t stream) {
    const float* x  = (const float*)d_in[0];
    const int*   ei = (const int*)d_in[1];
    const int*   pe = (const int*)d_in[2];
    const int*   ng = (const int*)d_in[3];
    const float* W1 = (const float*)d_in[4];
    const float* b1 = (const float*)d_in[5];
    const float* W2 = (const float*)d_in[6];
    const float* b2 = (const float*)d_in[7];
    float* out = (float*)d_out;

    const int F_IN = 256;
    const int n  = in_sizes[0] / F_IN;     // 100000
    const int E  = in_sizes[1] / 2;        // 1600000
    const int EP = in_sizes[2] / 2;        // 100000

    const int* row = ei;
    const int* col = ei + E;

    // ---- workspace layout (256B aligned) ----
    uint8_t* w = (uint8_t*)d_ws;
    auto alloc = [&](size_t bytes) {
        uint8_t* p = w;
        w += (bytes + 255) & ~(size_t)255;
        return p;
    };
    int*   cnt    = (int*)alloc((size_t)n * 4);
    float* dinv   = (float*)alloc((size_t)n * 4);
    int*   rowptr = (int*)alloc((size_t)(n + 1) * 4);
    int*   incl   = (int*)alloc((size_t)n * 4);
    int*   bsum   = (int*)alloc(512);
    int*   csr    = (int*)alloc((size_t)E * 4);
    float* bufA   = (float*)alloc((size_t)n * 128 * 4);   // h', then {t2', h2}
    float* bufB   = (float*)alloc((size_t)n * 128 * 4);   // h1
    float* h  = bufA;
    float* h1 = bufB;
    float* t2 = bufA;                      // reuse: h' dead after spmm1
    float* h2 = bufA + (size_t)n * 64;     // disjoint from t2

    // ---- zero degree counters (ws is poisoned 0xAA every call) ----
    hipMemsetAsync(cnt, 0, (size_t)n * 4, stream);

    const int TPB = 256;
    int ebl = (E + TPB - 1) / TPB;
    int nbl = (n + TPB - 1) / TPB;
    int nscan = (n + 1023) / 1024;

    k_hist<<<ebl, TPB, 0, stream>>>(col, cnt, E);
    k_dinv<<<nbl, TPB, 0, stream>>>(cnt, dinv, n);
    k_scan1<<<nscan, 1024, 0, stream>>>(cnt, incl, bsum, n);
    k_scan2<<<1, 128, 0, stream>>>(bsum, nscan);
    k_scan3<<<nbl, TPB, 0, stream>>>(incl, bsum, cnt, rowptr, n, E);
    k_fill<<<ebl, TPB, 0, stream>>>(row, col, rowptr, cnt, csr, E);   // consumes cnt

    // layer 1: h' = (x @ W1)*dinv ; h1 = relu(dinv*(sum h'[src] + h'[v]) + b1)
    sgemm_kernel<128, 128, 32, 256><<<(n + 127) / 128, 256, 0, stream>>>(x, W1, h, dinv, n, F_IN);
    k_spmm<128, true><<<(n + 3) / 4, 256, 0, stream>>>(h, rowptr, csr, dinv, b1, h1, n);

    // layer 2: t2' = (h1 @ W2)*dinv ; h2 = dinv*(sum t2'[src] + t2'[v]) + b2
    sgemm_kernel<128, 64, 32, 128><<<(n + 127) / 128, 128, 0, stream>>>(h1, W2, t2, dinv, n, 128);
    k_spmm<64, false><<<(n + 3) / 4, 256, 0, stream>>>(t2, rowptr, csr, dinv, b2, h2, n);

    // link prediction dots: 16 lanes per edge
    int ne2 = 2 * EP;
    k_dot<<<(ne2 + 15) / 16, TPB, 0, stream>>>(h2, pe, ng, out, EP, ne2);
}

// Round 6
// 603.051 us; speedup vs baseline: 1.1887x; 1.0489x over previous
//
#include <hip/hip_runtime.h>
#include <hip/hip_bf16.h>
#include <cstdint>
#include <cstddef>

// ---------------------------------------------------------------------------
// GCN link predictor: h1 = relu(Â(xW1)+b1); h2 = Â(h1W2)+b2; out = rowdot(h2[i],h2[j])
// Â built as CSR-by-destination each call (histogram -> scan -> fill).
// dinv[src] folded into GEMM epilogue: h' = (x@W)*dinv[row]; aggregation = pure sum.
// GEMMs: split-bf16 MFMA (a=hi+lo, W=hi+lo; hi*Whi + hi*Wlo + lo*Whi), f32 acc.
//        No LDS; A fragments from global; W pre-transposed/split to bf16 by pre-pass.
// SpMM: full-wave broadcast gather, 8-deep unroll for MLP.
// ---------------------------------------------------------------------------

typedef float f32x4 __attribute__((ext_vector_type(4)));
typedef short bf16x8 __attribute__((ext_vector_type(8)));

__device__ __forceinline__ unsigned short bf16rne(float f) {
    uint32_t u = __float_as_uint(f);
    u += 0x7fff + ((u >> 16) & 1);          // round-to-nearest-even
    return (unsigned short)(u >> 16);
}

__device__ __forceinline__ void cvt8(const float* a, bf16x8& hi, bf16x8& lo) {
    #pragma unroll
    for (int j = 0; j < 8; ++j) {
        float f = a[j];
        unsigned short h = bf16rne(f);
        float hf = __uint_as_float(((uint32_t)h) << 16);
        unsigned short l = bf16rne(f - hf);
        hi[j] = (short)h;
        lo[j] = (short)l;
    }
}

// ---------------- degree histogram ----------------
__global__ void k_hist(const int* __restrict__ col, int* __restrict__ cnt, int E) {
    int e = blockIdx.x * blockDim.x + threadIdx.x;
    if (e < E) atomicAdd(&cnt[col[e]], 1);
}

__global__ void k_dinv(const int* __restrict__ cnt, float* __restrict__ dinv, int n) {
    int v = blockIdx.x * blockDim.x + threadIdx.x;
    if (v < n) dinv[v] = rsqrtf((float)(cnt[v] + 1));  // +1 self loop
}

// ---------------- exclusive scan over cnt -> rowptr ----------------
__global__ void k_scan1(const int* __restrict__ cnt, int* __restrict__ incl,
                        int* __restrict__ bsum, int n) {
    __shared__ int s[1024];
    int tid = threadIdx.x;
    int g = blockIdx.x * 1024 + tid;
    s[tid] = (g < n) ? cnt[g] : 0;
    __syncthreads();
    for (int off = 1; off < 1024; off <<= 1) {
        int add = (tid >= off) ? s[tid - off] : 0;
        __syncthreads();
        s[tid] += add;
        __syncthreads();
    }
    if (g < n) incl[g] = s[tid];
    if (tid == 1023) bsum[blockIdx.x] = s[1023];
}

// parallel block-sum scan (nb <= 128)
__global__ void k_scan2(int* bsum, int nb) {
    __shared__ int s[128];
    int t = threadIdx.x;
    int v = (t < nb) ? bsum[t] : 0;
    s[t] = v;
    __syncthreads();
    for (int off = 1; off < 128; off <<= 1) {
        int add = (t >= off) ? s[t - off] : 0;
        __syncthreads();
        s[t] += add;
        __syncthreads();
    }
    if (t < nb) bsum[t] = s[t] - v;   // exclusive
}

__global__ void k_scan3(const int* __restrict__ incl, const int* __restrict__ bsum,
                        const int* __restrict__ cnt, int* __restrict__ rowptr,
                        int n, int E) {
    int v = blockIdx.x * blockDim.x + threadIdx.x;
    if (v < n) rowptr[v] = incl[v] + bsum[v >> 10] - cnt[v];
    if (v == 0) rowptr[n] = E;
}

// ---------------- CSR fill: reuse cnt as a countdown cursor ----------------
__global__ void k_fill(const int* __restrict__ row, const int* __restrict__ col,
                       const int* __restrict__ rowptr, int* __restrict__ cnt,
                       int* __restrict__ csr, int E) {
    int e = blockIdx.x * blockDim.x + threadIdx.x;
    if (e < E) {
        int c = col[e];
        int old = atomicSub(&cnt[c], 1);      // old in [1..deg], unique slot
        csr[rowptr[c] + old - 1] = row[e];
    }
}

// ---------------- W pre-pass: W[K][N] f32 -> WT[N][K] bf16 hi/lo ----------------
__global__ void k_wsplit(const float* __restrict__ W, unsigned short* __restrict__ hi,
                         unsigned short* __restrict__ lo, int K, int N) {
    int idx = blockIdx.x * blockDim.x + threadIdx.x;
    if (idx < K * N) {
        int k = idx / N, c = idx % N;
        float f = W[idx];
        unsigned short h = bf16rne(f);
        float hf = __uint_as_float(((uint32_t)h) << 16);
        unsigned short l = bf16rne(f - hf);
        hi[(size_t)c * K + k] = h;
        lo[(size_t)c * K + k] = l;
    }
}

// ---------------- split-bf16 MFMA GEMM: C[M,N] = (A[M,K] @ W[K,N]) * rscale[row]
// W given as WT hi/lo [N][K] bf16. Block: 256 thr = 4 waves, each 32 rows; BN = N.
// A frag: row = lane&15, k = (lane>>4)*8 + j (8 contiguous f32 -> hi/lo bf16).
// B frag: col = lane&15, same k slice (16B contiguous from WT).
// C/D:    col = lane&15, row = (lane>>4)*4 + reg   [m89-verified mapping]
template<int N, int K>
__launch_bounds__(256)
__global__ void gemm_mfma(const float* __restrict__ A, const unsigned short* __restrict__ BThi,
                          const unsigned short* __restrict__ BTlo, float* __restrict__ C,
                          const float* __restrict__ rscale, int M) {
    constexpr int NT = N / 16;
    const int lane = threadIdx.x & 63;
    const int w = threadIdx.x >> 6;
    const int rb = blockIdx.x * 128 + w * 32;
    const int c15 = lane & 15;
    const int ko = (lane >> 4) * 8;
    const int rA0 = min(rb + c15, M - 1);        // clamped loads; stores predicated
    const int rA1 = min(rb + 16 + c15, M - 1);

    f32x4 acc[2][NT] = {};

    for (int kt = 0; kt < K; kt += 32) {
        const float* a0p = A + (size_t)rA0 * K + kt + ko;
        const float* a1p = A + (size_t)rA1 * K + kt + ko;
        float4 p0 = *(const float4*)a0p, q0 = *(const float4*)(a0p + 4);
        float4 p1 = *(const float4*)a1p, q1 = *(const float4*)(a1p + 4);
        float ar0[8] = {p0.x, p0.y, p0.z, p0.w, q0.x, q0.y, q0.z, q0.w};
        float ar1[8] = {p1.x, p1.y, p1.z, p1.w, q1.x, q1.y, q1.z, q1.w};
        bf16x8 ah0, al0, ah1, al1;
        cvt8(ar0, ah0, al0);
        cvt8(ar1, ah1, al1);

        #pragma unroll
        for (int nt = 0; nt < NT; ++nt) {
            const size_t boff = (size_t)(nt * 16 + c15) * K + kt + ko;
            bf16x8 bh = *(const bf16x8*)(BThi + boff);
            bf16x8 bl = *(const bf16x8*)(BTlo + boff);
            acc[0][nt] = __builtin_amdgcn_mfma_f32_16x16x32_bf16(ah0, bh, acc[0][nt], 0, 0, 0);
            acc[1][nt] = __builtin_amdgcn_mfma_f32_16x16x32_bf16(ah1, bh, acc[1][nt], 0, 0, 0);
            acc[0][nt] = __builtin_amdgcn_mfma_f32_16x16x32_bf16(al0, bh, acc[0][nt], 0, 0, 0);
            acc[1][nt] = __builtin_amdgcn_mfma_f32_16x16x32_bf16(al1, bh, acc[1][nt], 0, 0, 0);
            acc[0][nt] = __builtin_amdgcn_mfma_f32_16x16x32_bf16(ah0, bl, acc[0][nt], 0, 0, 0);
            acc[1][nt] = __builtin_amdgcn_mfma_f32_16x16x32_bf16(ah1, bl, acc[1][nt], 0, 0, 0);
        }
    }

    const int r4 = (lane >> 4) * 4;
    #pragma unroll
    for (int mt = 0; mt < 2; ++mt) {
        #pragma unroll
        for (int j = 0; j < 4; ++j) {
            int grow = rb + mt * 16 + r4 + j;
            if (grow < M) {
                float rs = rscale[grow];
                float* cp = C + (size_t)grow * N + c15;
                #pragma unroll
                for (int nt = 0; nt < NT; ++nt)
                    cp[nt * 16] = acc[mt][nt][j] * rs;
            }
        }
    }
}

// ---------------- pull-SpMM on prescaled hp: out[v] = dinv[v]*(sum_e hp[src] + hp[v]) + b
template<int F, bool RELU>
__launch_bounds__(256)
__global__ void k_spmm(const float* __restrict__ hp, const int* __restrict__ rowptr,
                       const int* __restrict__ csr, const float* __restrict__ dinv,
                       const float* __restrict__ bias, float* __restrict__ out, int n) {
    const int wid  = (blockIdx.x * 256 + threadIdx.x) >> 6;   // wave id = node id
    const int lane = threadIdx.x & 63;
    if (wid >= n) return;
    const int v = wid;
    const int beg = rowptr[v], end = rowptr[v + 1];

    float acc0 = 0.f, acc1 = 0.f;   // F=128: features {2*lane, 2*lane+1}; F=64: {lane}

    for (int base = beg; base < end; base += 64) {
        const int e  = base + lane;
        const int sv = (e < end) ? csr[e] : 0;
        const int m  = min(64, end - base);
        int j = 0;
        for (; j + 8 <= m; j += 8) {        // 8 independent gathers in flight
            int s0 = __shfl(sv, j + 0, 64), s1 = __shfl(sv, j + 1, 64);
            int s2 = __shfl(sv, j + 2, 64), s3 = __shfl(sv, j + 3, 64);
            int s4 = __shfl(sv, j + 4, 64), s5 = __shfl(sv, j + 5, 64);
            int s6 = __shfl(sv, j + 6, 64), s7 = __shfl(sv, j + 7, 64);
            if (F == 128) {
                float2 a0 = *(const float2*)(hp + (size_t)s0 * F + lane * 2);
                float2 a1 = *(const float2*)(hp + (size_t)s1 * F + lane * 2);
                float2 a2 = *(const float2*)(hp + (size_t)s2 * F + lane * 2);
                float2 a3 = *(const float2*)(hp + (size_t)s3 * F + lane * 2);
                float2 a4 = *(const float2*)(hp + (size_t)s4 * F + lane * 2);
                float2 a5 = *(const float2*)(hp + (size_t)s5 * F + lane * 2);
                float2 a6 = *(const float2*)(hp + (size_t)s6 * F + lane * 2);
                float2 a7 = *(const float2*)(hp + (size_t)s7 * F + lane * 2);
                acc0 += ((a0.x + a1.x) + (a2.x + a3.x)) + ((a4.x + a5.x) + (a6.x + a7.x));
                acc1 += ((a0.y + a1.y) + (a2.y + a3.y)) + ((a4.y + a5.y) + (a6.y + a7.y));
            } else {
                float a0 = hp[(size_t)s0 * F + lane], a1 = hp[(size_t)s1 * F + lane];
                float a2 = hp[(size_t)s2 * F + lane], a3 = hp[(size_t)s3 * F + lane];
                float a4 = hp[(size_t)s4 * F + lane], a5 = hp[(size_t)s5 * F + lane];
                float a6 = hp[(size_t)s6 * F + lane], a7 = hp[(size_t)s7 * F + lane];
                acc0 += ((a0 + a1) + (a2 + a3)) + ((a4 + a5) + (a6 + a7));
            }
        }
        for (; j < m; ++j) {
            int s = __shfl(sv, j, 64);
            if (F == 128) {
                float2 a = *(const float2*)(hp + (size_t)s * F + lane * 2);
                acc0 += a.x; acc1 += a.y;
            } else {
                acc0 += hp[(size_t)s * F + lane];
            }
        }
    }

    const float d = dinv[v];
    if (F == 128) {
        float2 self = *(const float2*)(hp + (size_t)v * F + lane * 2);
        float r0 = (acc0 + self.x) * d + bias[lane * 2];
        float r1 = (acc1 + self.y) * d + bias[lane * 2 + 1];
        if (RELU) { r0 = fmaxf(r0, 0.f); r1 = fmaxf(r1, 0.f); }
        *(float2*)(out + (size_t)v * F + lane * 2) = make_float2(r0, r1);
    } else {
        float self = hp[(size_t)v * F + lane];
        float r = (acc0 + self) * d + bias[lane];
        if (RELU) r = fmaxf(r, 0.f);
        out[(size_t)v * F + lane] = r;
    }
}

// ---------------- edge dot: 16 lanes per edge, float4 loads ----------------
__launch_bounds__(256)
__global__ void k_dot(const float* __restrict__ h2, const int* __restrict__ pos,
                      const int* __restrict__ neg, float* __restrict__ out,
                      int ep, int ne2) {
    int gid = (blockIdx.x * 256 + threadIdx.x) >> 4;   // 16-lane group = one edge
    int l = threadIdx.x & 15;
    if (gid >= ne2) return;
    const int* p = (gid < ep) ? pos : neg;
    int e = (gid < ep) ? gid : gid - ep;
    int a = p[e];        // te[0] = source
    int b = p[ep + e];   // te[1] = target
    float4 va = *(const float4*)(h2 + (size_t)a * 64 + l * 4);
    float4 vb = *(const float4*)(h2 + (size_t)b * 64 + l * 4);
    float s = va.x * vb.x + va.y * vb.y + va.z * vb.z + va.w * vb.w;
    s += __shfl_xor(s, 8, 64);
    s += __shfl_xor(s, 4, 64);
    s += __shfl_xor(s, 2, 64);
    s += __shfl_xor(s, 1, 64);
    if (l == 0) out[gid] = s;
}

// ---------------------------------------------------------------------------
extern "C" void kernel_launch(void* const* d_in, const int* in_sizes, int n_in,
                              void* d_out, int out_size, void* d_ws, size_t ws_size,
                              hipStream_t stream) {
    const float* x  = (const float*)d_in[0];
    const int*   ei = (const int*)d_in[1];
    const int*   pe = (const int*)d_in[2];
    const int*   ng = (const int*)d_in[3];
    const float* W1 = (const float*)d_in[4];
    const float* b1 = (const float*)d_in[5];
    const float* W2 = (const float*)d_in[6];
    const float* b2 = (const float*)d_in[7];
    float* out = (float*)d_out;

    const int F_IN = 256, H1 = 128, H2 = 64;
    const int n  = in_sizes[0] / F_IN;     // 100000
    const int E  = in_sizes[1] / 2;        // 1600000
    const int EP = in_sizes[2] / 2;        // 100000

    const int* row = ei;
    const int* col = ei + E;

    // ---- workspace layout (256B aligned) ----
    uint8_t* w = (uint8_t*)d_ws;
    auto alloc = [&](size_t bytes) {
        uint8_t* p = w;
        w += (bytes + 255) & ~(size_t)255;
        return p;
    };
    int*   cnt    = (int*)alloc((size_t)n * 4);
    float* dinv   = (float*)alloc((size_t)n * 4);
    int*   rowptr = (int*)alloc((size_t)(n + 1) * 4);
    int*   incl   = (int*)alloc((size_t)n * 4);
    int*   bsum   = (int*)alloc(512);
    int*   csr    = (int*)alloc((size_t)E * 4);
    unsigned short* wt1hi = (unsigned short*)alloc((size_t)F_IN * H1 * 2);
    unsigned short* wt1lo = (unsigned short*)alloc((size_t)F_IN * H1 * 2);
    unsigned short* wt2hi = (unsigned short*)alloc((size_t)H1 * H2 * 2);
    unsigned short* wt2lo = (unsigned short*)alloc((size_t)H1 * H2 * 2);
    float* bufA   = (float*)alloc((size_t)n * 128 * 4);   // h', then {t2', h2}
    float* bufB   = (float*)alloc((size_t)n * 128 * 4);   // h1
    float* h  = bufA;
    float* h1 = bufB;
    float* t2 = bufA;                      // reuse: h' dead after spmm1
    float* h2 = bufA + (size_t)n * 64;     // disjoint from t2

    // ---- zero degree counters (ws is poisoned 0xAA every call) ----
    hipMemsetAsync(cnt, 0, (size_t)n * 4, stream);

    const int TPB = 256;
    int ebl = (E + TPB - 1) / TPB;
    int nbl = (n + TPB - 1) / TPB;
    int nscan = (n + 1023) / 1024;

    // W pre-split (tiny, independent)
    k_wsplit<<<(F_IN * H1 + 255) / 256, 256, 0, stream>>>(W1, wt1hi, wt1lo, F_IN, H1);
    k_wsplit<<<(H1 * H2 + 255) / 256, 256, 0, stream>>>(W2, wt2hi, wt2lo, H1, H2);

    k_hist<<<ebl, TPB, 0, stream>>>(col, cnt, E);
    k_dinv<<<nbl, TPB, 0, stream>>>(cnt, dinv, n);
    k_scan1<<<nscan, 1024, 0, stream>>>(cnt, incl, bsum, n);
    k_scan2<<<1, 128, 0, stream>>>(bsum, nscan);
    k_scan3<<<nbl, TPB, 0, stream>>>(incl, bsum, cnt, rowptr, n, E);
    k_fill<<<ebl, TPB, 0, stream>>>(row, col, rowptr, cnt, csr, E);   // consumes cnt

    // layer 1: h' = (x @ W1)*dinv ; h1 = relu(dinv*(sum h'[src] + h'[v]) + b1)
    gemm_mfma<128, 256><<<(n + 127) / 128, 256, 0, stream>>>(x, wt1hi, wt1lo, h, dinv, n);
    k_spmm<128, true><<<(n + 3) / 4, 256, 0, stream>>>(h, rowptr, csr, dinv, b1, h1, n);

    // layer 2: t2' = (h1 @ W2)*dinv ; h2 = dinv*(sum t2'[src] + t2'[v]) + b2
    gemm_mfma<64, 128><<<(n + 127) / 128, 256, 0, stream>>>(h1, wt2hi, wt2lo, t2, dinv, n);
    k_spmm<64, false><<<(n + 3) / 4, 256, 0, stream>>>(t2, rowptr, csr, dinv, b2, h2, n);

    // link prediction dots: 16 lanes per edge
    int ne2 = 2 * EP;
    k_dot<<<(ne2 + 15) / 16, TPB, 0, stream>>>(h2, pe, ng, out, EP, ne2);
}

// Round 7
// 543.230 us; speedup vs baseline: 1.3196x; 1.1101x over previous
//
#include <hip/hip_runtime.h>
#include <hip/hip_bf16.h>
#include <cstdint>
#include <cstddef>

// ---------------------------------------------------------------------------
// GCN link predictor: h1 = relu(Â(xW1)+b1); h2 = Â(h1W2)+b2; out = rowdot(h2[i],h2[j])
// Â built as CSR-by-destination each call (histogram -> scan -> fill).
// dinv[src] folded into GEMM epilogue: h' = (x@W)*dinv[row]; aggregation = pure sum.
// GEMMs: split-bf16 MFMA (a=hi+lo, W=hi+lo; hi*Whi + hi*Wlo + lo*Whi), f32 acc.
// Aggregation inputs h', t2' stored BF16 (halves random-gather traffic; quant err
// ~1e-4 per dot, far under the 3.9e-3 floor). h1 stays f32 (feeds split-GEMM).
// SpMM: full-wave broadcast gather, 8-deep unroll for MLP.
// ---------------------------------------------------------------------------

typedef float f32x4 __attribute__((ext_vector_type(4)));
typedef short bf16x8 __attribute__((ext_vector_type(8)));

__device__ __forceinline__ unsigned short bf16rne(float f) {
    uint32_t u = __float_as_uint(f);
    u += 0x7fff + ((u >> 16) & 1);          // round-to-nearest-even
    return (unsigned short)(u >> 16);
}

__device__ __forceinline__ float bfhi(uint32_t w) {   // high u16 -> f32
    return __uint_as_float(w & 0xffff0000u);
}
__device__ __forceinline__ float bflo(uint32_t w) {   // low u16 -> f32
    return __uint_as_float(w << 16);
}

__device__ __forceinline__ void cvt8(const float* a, bf16x8& hi, bf16x8& lo) {
    #pragma unroll
    for (int j = 0; j < 8; ++j) {
        float f = a[j];
        unsigned short h = bf16rne(f);
        float hf = __uint_as_float(((uint32_t)h) << 16);
        unsigned short l = bf16rne(f - hf);
        hi[j] = (short)h;
        lo[j] = (short)l;
    }
}

// ---------------- degree histogram ----------------
__global__ void k_hist(const int* __restrict__ col, int* __restrict__ cnt, int E) {
    int e = blockIdx.x * blockDim.x + threadIdx.x;
    if (e < E) atomicAdd(&cnt[col[e]], 1);
}

__global__ void k_dinv(const int* __restrict__ cnt, float* __restrict__ dinv, int n) {
    int v = blockIdx.x * blockDim.x + threadIdx.x;
    if (v < n) dinv[v] = rsqrtf((float)(cnt[v] + 1));  // +1 self loop
}

// ---------------- exclusive scan over cnt -> rowptr ----------------
__global__ void k_scan1(const int* __restrict__ cnt, int* __restrict__ incl,
                        int* __restrict__ bsum, int n) {
    __shared__ int s[1024];
    int tid = threadIdx.x;
    int g = blockIdx.x * 1024 + tid;
    s[tid] = (g < n) ? cnt[g] : 0;
    __syncthreads();
    for (int off = 1; off < 1024; off <<= 1) {
        int add = (tid >= off) ? s[tid - off] : 0;
        __syncthreads();
        s[tid] += add;
        __syncthreads();
    }
    if (g < n) incl[g] = s[tid];
    if (tid == 1023) bsum[blockIdx.x] = s[1023];
}

// parallel block-sum scan (nb <= 128)
__global__ void k_scan2(int* bsum, int nb) {
    __shared__ int s[128];
    int t = threadIdx.x;
    int v = (t < nb) ? bsum[t] : 0;
    s[t] = v;
    __syncthreads();
    for (int off = 1; off < 128; off <<= 1) {
        int add = (t >= off) ? s[t - off] : 0;
        __syncthreads();
        s[t] += add;
        __syncthreads();
    }
    if (t < nb) bsum[t] = s[t] - v;   // exclusive
}

__global__ void k_scan3(const int* __restrict__ incl, const int* __restrict__ bsum,
                        const int* __restrict__ cnt, int* __restrict__ rowptr,
                        int n, int E) {
    int v = blockIdx.x * blockDim.x + threadIdx.x;
    if (v < n) rowptr[v] = incl[v] + bsum[v >> 10] - cnt[v];
    if (v == 0) rowptr[n] = E;
}

// ---------------- CSR fill: reuse cnt as a countdown cursor ----------------
__global__ void k_fill(const int* __restrict__ row, const int* __restrict__ col,
                       const int* __restrict__ rowptr, int* __restrict__ cnt,
                       int* __restrict__ csr, int E) {
    int e = blockIdx.x * blockDim.x + threadIdx.x;
    if (e < E) {
        int c = col[e];
        int old = atomicSub(&cnt[c], 1);      // old in [1..deg], unique slot
        csr[rowptr[c] + old - 1] = row[e];
    }
}

// ---------------- W pre-pass: W[K][N] f32 -> WT[N][K] bf16 hi/lo ----------------
__global__ void k_wsplit(const float* __restrict__ W, unsigned short* __restrict__ hi,
                         unsigned short* __restrict__ lo, int K, int N) {
    int idx = blockIdx.x * blockDim.x + threadIdx.x;
    if (idx < K * N) {
        int k = idx / N, c = idx % N;
        float f = W[idx];
        unsigned short h = bf16rne(f);
        float hf = __uint_as_float(((uint32_t)h) << 16);
        unsigned short l = bf16rne(f - hf);
        hi[(size_t)c * K + k] = h;
        lo[(size_t)c * K + k] = l;
    }
}

// ---------------- split-bf16 MFMA GEMM: C[M,N] = (A[M,K] @ W[K,N]) * rscale[row]
// W given as WT hi/lo [N][K] bf16. Block: 256 thr = 4 waves, each 32 rows; BN = N.
// OBF16: store output rounded to bf16 (u16), else f32.
template<int N, int K, bool OBF16>
__launch_bounds__(256)
__global__ void gemm_mfma(const float* __restrict__ A, const unsigned short* __restrict__ BThi,
                          const unsigned short* __restrict__ BTlo, void* __restrict__ Cv,
                          const float* __restrict__ rscale, int M) {
    constexpr int NT = N / 16;
    const int lane = threadIdx.x & 63;
    const int w = threadIdx.x >> 6;
    const int rb = blockIdx.x * 128 + w * 32;
    const int c15 = lane & 15;
    const int ko = (lane >> 4) * 8;
    const int rA0 = min(rb + c15, M - 1);        // clamped loads; stores predicated
    const int rA1 = min(rb + 16 + c15, M - 1);

    f32x4 acc[2][NT] = {};

    for (int kt = 0; kt < K; kt += 32) {
        const float* a0p = A + (size_t)rA0 * K + kt + ko;
        const float* a1p = A + (size_t)rA1 * K + kt + ko;
        float4 p0 = *(const float4*)a0p, q0 = *(const float4*)(a0p + 4);
        float4 p1 = *(const float4*)a1p, q1 = *(const float4*)(a1p + 4);
        float ar0[8] = {p0.x, p0.y, p0.z, p0.w, q0.x, q0.y, q0.z, q0.w};
        float ar1[8] = {p1.x, p1.y, p1.z, p1.w, q1.x, q1.y, q1.z, q1.w};
        bf16x8 ah0, al0, ah1, al1;
        cvt8(ar0, ah0, al0);
        cvt8(ar1, ah1, al1);

        #pragma unroll
        for (int nt = 0; nt < NT; ++nt) {
            const size_t boff = (size_t)(nt * 16 + c15) * K + kt + ko;
            bf16x8 bh = *(const bf16x8*)(BThi + boff);
            bf16x8 bl = *(const bf16x8*)(BTlo + boff);
            acc[0][nt] = __builtin_amdgcn_mfma_f32_16x16x32_bf16(ah0, bh, acc[0][nt], 0, 0, 0);
            acc[1][nt] = __builtin_amdgcn_mfma_f32_16x16x32_bf16(ah1, bh, acc[1][nt], 0, 0, 0);
            acc[0][nt] = __builtin_amdgcn_mfma_f32_16x16x32_bf16(al0, bh, acc[0][nt], 0, 0, 0);
            acc[1][nt] = __builtin_amdgcn_mfma_f32_16x16x32_bf16(al1, bh, acc[1][nt], 0, 0, 0);
            acc[0][nt] = __builtin_amdgcn_mfma_f32_16x16x32_bf16(ah0, bl, acc[0][nt], 0, 0, 0);
            acc[1][nt] = __builtin_amdgcn_mfma_f32_16x16x32_bf16(ah1, bl, acc[1][nt], 0, 0, 0);
        }
    }

    const int r4 = (lane >> 4) * 4;
    #pragma unroll
    for (int mt = 0; mt < 2; ++mt) {
        #pragma unroll
        for (int j = 0; j < 4; ++j) {
            int grow = rb + mt * 16 + r4 + j;
            if (grow < M) {
                float rs = rscale[grow];
                if (OBF16) {
                    unsigned short* cp = (unsigned short*)Cv + (size_t)grow * N + c15;
                    #pragma unroll
                    for (int nt = 0; nt < NT; ++nt)
                        cp[nt * 16] = bf16rne(acc[mt][nt][j] * rs);
                } else {
                    float* cp = (float*)Cv + (size_t)grow * N + c15;
                    #pragma unroll
                    for (int nt = 0; nt < NT; ++nt)
                        cp[nt * 16] = acc[mt][nt][j] * rs;
                }
            }
        }
    }
}

// ---------------- pull-SpMM on bf16 prescaled hp: out = dinv*(sum hp[src] + hp[v]) + b
// F=128: lane loads u32 = 2 packed bf16 (feats 2l,2l+1). F=64: lane loads u16 (feat l).
// Output f32. Full-wave broadcast, 8-deep unroll.
template<int F, bool RELU>
__launch_bounds__(256)
__global__ void k_spmm(const unsigned short* __restrict__ hpu, const int* __restrict__ rowptr,
                       const int* __restrict__ csr, const float* __restrict__ dinv,
                       const float* __restrict__ bias, float* __restrict__ out, int n) {
    const int wid  = (blockIdx.x * 256 + threadIdx.x) >> 6;   // wave id = node id
    const int lane = threadIdx.x & 63;
    if (wid >= n) return;
    const int v = wid;
    const int beg = rowptr[v], end = rowptr[v + 1];
    const uint32_t* hp32 = (const uint32_t*)hpu;   // F=128 path: row = 64 u32

    float acc0 = 0.f, acc1 = 0.f;   // F=128: feats {2l, 2l+1}; F=64: {l}

    for (int base = beg; base < end; base += 64) {
        const int e  = base + lane;
        const int sv = (e < end) ? csr[e] : 0;
        const int m  = min(64, end - base);
        int j = 0;
        for (; j + 8 <= m; j += 8) {        // 8 independent gathers in flight
            int s0 = __shfl(sv, j + 0, 64), s1 = __shfl(sv, j + 1, 64);
            int s2 = __shfl(sv, j + 2, 64), s3 = __shfl(sv, j + 3, 64);
            int s4 = __shfl(sv, j + 4, 64), s5 = __shfl(sv, j + 5, 64);
            int s6 = __shfl(sv, j + 6, 64), s7 = __shfl(sv, j + 7, 64);
            if (F == 128) {
                uint32_t w0 = hp32[(size_t)s0 * 64 + lane];
                uint32_t w1 = hp32[(size_t)s1 * 64 + lane];
                uint32_t w2 = hp32[(size_t)s2 * 64 + lane];
                uint32_t w3 = hp32[(size_t)s3 * 64 + lane];
                uint32_t w4 = hp32[(size_t)s4 * 64 + lane];
                uint32_t w5 = hp32[(size_t)s5 * 64 + lane];
                uint32_t w6 = hp32[(size_t)s6 * 64 + lane];
                uint32_t w7 = hp32[(size_t)s7 * 64 + lane];
                acc0 += ((bflo(w0) + bflo(w1)) + (bflo(w2) + bflo(w3)))
                      + ((bflo(w4) + bflo(w5)) + (bflo(w6) + bflo(w7)));
                acc1 += ((bfhi(w0) + bfhi(w1)) + (bfhi(w2) + bfhi(w3)))
                      + ((bfhi(w4) + bfhi(w5)) + (bfhi(w6) + bfhi(w7)));
            } else {
                float a0 = bflo(hpu[(size_t)s0 * F + lane]);
                float a1 = bflo(hpu[(size_t)s1 * F + lane]);
                float a2 = bflo(hpu[(size_t)s2 * F + lane]);
                float a3 = bflo(hpu[(size_t)s3 * F + lane]);
                float a4 = bflo(hpu[(size_t)s4 * F + lane]);
                float a5 = bflo(hpu[(size_t)s5 * F + lane]);
                float a6 = bflo(hpu[(size_t)s6 * F + lane]);
                float a7 = bflo(hpu[(size_t)s7 * F + lane]);
                acc0 += ((a0 + a1) + (a2 + a3)) + ((a4 + a5) + (a6 + a7));
            }
        }
        for (; j < m; ++j) {
            int s = __shfl(sv, j, 64);
            if (F == 128) {
                uint32_t w = hp32[(size_t)s * 64 + lane];
                acc0 += bflo(w); acc1 += bfhi(w);
            } else {
                acc0 += bflo(hpu[(size_t)s * F + lane]);
            }
        }
    }

    const float d = dinv[v];
    if (F == 128) {
        uint32_t ws = hp32[(size_t)v * 64 + lane];
        float r0 = (acc0 + bflo(ws)) * d + bias[lane * 2];
        float r1 = (acc1 + bfhi(ws)) * d + bias[lane * 2 + 1];
        if (RELU) { r0 = fmaxf(r0, 0.f); r1 = fmaxf(r1, 0.f); }
        *(float2*)(out + (size_t)v * F + lane * 2) = make_float2(r0, r1);
    } else {
        float self = bflo(hpu[(size_t)v * F + lane]);
        float r = (acc0 + self) * d + bias[lane];
        if (RELU) r = fmaxf(r, 0.f);
        out[(size_t)v * F + lane] = r;
    }
}

// ---------------- edge dot: 16 lanes per edge, float4 loads ----------------
__launch_bounds__(256)
__global__ void k_dot(const float* __restrict__ h2, const int* __restrict__ pos,
                      const int* __restrict__ neg, float* __restrict__ out,
                      int ep, int ne2) {
    int gid = (blockIdx.x * 256 + threadIdx.x) >> 4;   // 16-lane group = one edge
    int l = threadIdx.x & 15;
    if (gid >= ne2) return;
    const int* p = (gid < ep) ? pos : neg;
    int e = (gid < ep) ? gid : gid - ep;
    int a = p[e];        // te[0] = source
    int b = p[ep + e];   // te[1] = target
    float4 va = *(const float4*)(h2 + (size_t)a * 64 + l * 4);
    float4 vb = *(const float4*)(h2 + (size_t)b * 64 + l * 4);
    float s = va.x * vb.x + va.y * vb.y + va.z * vb.z + va.w * vb.w;
    s += __shfl_xor(s, 8, 64);
    s += __shfl_xor(s, 4, 64);
    s += __shfl_xor(s, 2, 64);
    s += __shfl_xor(s, 1, 64);
    if (l == 0) out[gid] = s;
}

// ---------------------------------------------------------------------------
extern "C" void kernel_launch(void* const* d_in, const int* in_sizes, int n_in,
                              void* d_out, int out_size, void* d_ws, size_t ws_size,
                              hipStream_t stream) {
    const float* x  = (const float*)d_in[0];
    const int*   ei = (const int*)d_in[1];
    const int*   pe = (const int*)d_in[2];
    const int*   ng = (const int*)d_in[3];
    const float* W1 = (const float*)d_in[4];
    const float* b1 = (const float*)d_in[5];
    const float* W2 = (const float*)d_in[6];
    const float* b2 = (const float*)d_in[7];
    float* out = (float*)d_out;

    const int F_IN = 256, H1 = 128, H2 = 64;
    const int n  = in_sizes[0] / F_IN;     // 100000
    const int E  = in_sizes[1] / 2;        // 1600000
    const int EP = in_sizes[2] / 2;        // 100000

    const int* row = ei;
    const int* col = ei + E;

    // ---- workspace layout (256B aligned) ----
    uint8_t* w = (uint8_t*)d_ws;
    auto alloc = [&](size_t bytes) {
        uint8_t* p = w;
        w += (bytes + 255) & ~(size_t)255;
        return p;
    };
    int*   cnt    = (int*)alloc((size_t)n * 4);
    float* dinv   = (float*)alloc((size_t)n * 4);
    int*   rowptr = (int*)alloc((size_t)(n + 1) * 4);
    int*   incl   = (int*)alloc((size_t)n * 4);
    int*   bsum   = (int*)alloc(512);
    int*   csr    = (int*)alloc((size_t)E * 4);
    unsigned short* wt1hi = (unsigned short*)alloc((size_t)F_IN * H1 * 2);
    unsigned short* wt1lo = (unsigned short*)alloc((size_t)F_IN * H1 * 2);
    unsigned short* wt2hi = (unsigned short*)alloc((size_t)H1 * H2 * 2);
    unsigned short* wt2lo = (unsigned short*)alloc((size_t)H1 * H2 * 2);
    float* bufA   = (float*)alloc((size_t)n * 128 * 4);   // h'(bf16), t2'(bf16), h2(f32)
    float* bufB   = (float*)alloc((size_t)n * 128 * 4);   // h1 (f32)
    unsigned short* h  = (unsigned short*)bufA;           // bf16 [n][128]: bytes [0, 25.6M)
    float* h1 = bufB;                                     // f32  [n][128]
    unsigned short* t2 = (unsigned short*)bufA;           // bf16 [n][64]:  bytes [0, 12.8M) (h dead)
    float* h2 = bufA + (size_t)n * 64;                    // f32  [n][64]:  bytes [25.6M, 51.2M)

    // ---- zero degree counters (ws is poisoned 0xAA every call) ----
    hipMemsetAsync(cnt, 0, (size_t)n * 4, stream);

    const int TPB = 256;
    int ebl = (E + TPB - 1) / TPB;
    int nbl = (n + TPB - 1) / TPB;
    int nscan = (n + 1023) / 1024;

    // W pre-split (tiny, independent)
    k_wsplit<<<(F_IN * H1 + 255) / 256, 256, 0, stream>>>(W1, wt1hi, wt1lo, F_IN, H1);
    k_wsplit<<<(H1 * H2 + 255) / 256, 256, 0, stream>>>(W2, wt2hi, wt2lo, H1, H2);

    k_hist<<<ebl, TPB, 0, stream>>>(col, cnt, E);
    k_dinv<<<nbl, TPB, 0, stream>>>(cnt, dinv, n);
    k_scan1<<<nscan, 1024, 0, stream>>>(cnt, incl, bsum, n);
    k_scan2<<<1, 128, 0, stream>>>(bsum, nscan);
    k_scan3<<<nbl, TPB, 0, stream>>>(incl, bsum, cnt, rowptr, n, E);
    k_fill<<<ebl, TPB, 0, stream>>>(row, col, rowptr, cnt, csr, E);   // consumes cnt

    // layer 1: h' = bf16((x @ W1)*dinv) ; h1 = relu(dinv*(sum h'[src] + h'[v]) + b1)
    gemm_mfma<128, 256, true><<<(n + 127) / 128, 256, 0, stream>>>(x, wt1hi, wt1lo, h, dinv, n);
    k_spmm<128, true><<<(n + 3) / 4, 256, 0, stream>>>(h, rowptr, csr, dinv, b1, h1, n);

    // layer 2: t2' = bf16((h1 @ W2)*dinv) ; h2 = dinv*(sum t2'[src] + t2'[v]) + b2
    gemm_mfma<64, 128, true><<<(n + 127) / 128, 256, 0, stream>>>(h1, wt2hi, wt2lo, t2, dinv, n);
    k_spmm<64, false><<<(n + 3) / 4, 256, 0, stream>>>(t2, rowptr, csr, dinv, b2, h2, n);

    // link prediction dots: 16 lanes per edge
    int ne2 = 2 * EP;
    k_dot<<<(ne2 + 15) / 16, TPB, 0, stream>>>(h2, pe, ng, out, EP, ne2);
}